// Round 6
// baseline (212.394 us; speedup 1.0000x reference)
//
#include <hip/hip_runtime.h>
#include <hip/hip_bf16.h>

// Self-attention: y = softmax_causal((Xq Wq^T + bq)(Xk Wk^T + bk)^T / 32) (Xv Wv^T + bv)
// N=4, K=2048, M=DQ=DV=1024.
//
// Pipeline (bf16 MFMA, f32 accumulate):
//   0) cvt3 x2        : {query,key,value} and {Wq,Wk,Wv} -> bf16
//   1) gemm256_proj   : ALL THREE projections, 256x256 8-phase counted-vmcnt schedule
//                       (T3+T4+T5, m201 template), z selects tensor
//   2) transpose2d    : V [k][d] -> Vt [d][k]
//   3) gemm_bt<1>     : S = Qs . Kp^T (f32), causal block skip   (r5-verified 2-phase)
//   4) softmax_causal : causal softmax by index, bf16 P in-place over S
//   5) gemm_bt<2>     : y = P . Vt, K truncated at causal boundary, f32 out
//
// gemm256_proj schedule (per K-tile, 4 phases, quadrant order (0,0)(0,1)(1,1)(1,0)):
//   tile boundary: issue next tile's 8 wave-partitioned global_load_lds into buf^1,
//                  s_waitcnt vmcnt(8)  [NEVER 0 in steady state], s_barrier
//   each phase   : ds_read quadrant frags (A/B reused across phases) -> s_barrier ->
//                  setprio(1) -> 16 MFMA -> setprio(0) -> s_barrier
// All raw barriers/waits pinned with sched_barrier(0).
//
// Workspace (128 MiB): QKV bf16 [3][8192][1024] @0; Vt @48M; S f32 @64M
//   (overlap, dead before S: Xb @64M, Wb @112M)

typedef __bf16 bf16x8 __attribute__((ext_vector_type(8)));
typedef float  f32x4  __attribute__((ext_vector_type(4)));

#define BM 128
#define BN 128
#define BKK 64

__device__ __forceinline__ int swz(int row, int slot) {
    return row * 128 + (((slot) ^ (row & 7)) << 4);
}

__device__ __forceinline__ void gload16(const __bf16* g, __bf16* l) {
    __builtin_amdgcn_global_load_lds((const __attribute__((address_space(1))) void*)g,
                                     (__attribute__((address_space(3))) void*)l, 16, 0, 0);
}

// T1: bijective XCD-chunked remap (m204)
__device__ __forceinline__ void xcd_remap(int& bx, int& by, int& bz) {
    const int nx = gridDim.x, ny = gridDim.y;
    const int nwg = nx * ny * gridDim.z;
    const int flat = blockIdx.x + nx * (blockIdx.y + ny * blockIdx.z);
    const int q = nwg >> 3, r = nwg & 7;
    const int xcd = flat & 7, idx = flat >> 3;
    const int l = (xcd < r ? xcd * (q + 1) : r * (q + 1) + (xcd - r) * q) + idx;
    bx = l % nx; by = (l / nx) % ny; bz = l / (nx * ny);
}

// ======================= 256x256 8-phase projection GEMM =======================
// C[z][8192][1024] = X[z][8192][1024] . W[z][1024][1024]^T (+bias[z], z==0 *1/32)
template<int MH, int NH, bool DOA, bool DOB>
__device__ __forceinline__ void phase256(const char* LAb, const char* LBb,
    int wM, int wn, int g, int li,
    bf16x8 (&aF)[4][2], bf16x8 (&bF)[2][2], f32x4 (&acc)[8][4])
{
    if (DOA) {
#pragma unroll
        for (int i = 0; i < 4; i++)
#pragma unroll
            for (int kk = 0; kk < 2; kk++) {
                const int row = wM * 128 + MH * 64 + i * 16 + li;
                aF[i][kk] = *(const bf16x8*)(LAb + swz(row, kk * 4 + g));
            }
    }
    if (DOB) {
#pragma unroll
        for (int j = 0; j < 2; j++)
#pragma unroll
            for (int kk = 0; kk < 2; kk++) {
                const int row = wn * 64 + NH * 32 + j * 16 + li;
                bF[j][kk] = *(const bf16x8*)(LBb + swz(row, kk * 4 + g));
            }
    }
    __builtin_amdgcn_s_barrier();
    __builtin_amdgcn_sched_barrier(0);
    __builtin_amdgcn_s_setprio(1);
#pragma unroll
    for (int kk = 0; kk < 2; kk++)
#pragma unroll
        for (int i = 0; i < 4; i++)
#pragma unroll
            for (int j = 0; j < 2; j++)
                acc[MH * 4 + i][NH * 2 + j] = __builtin_amdgcn_mfma_f32_16x16x32_bf16(
                    aF[i][kk], bF[j][kk], acc[MH * 4 + i][NH * 2 + j], 0, 0, 0);
    __builtin_amdgcn_s_setprio(0);
    __builtin_amdgcn_s_barrier();
    __builtin_amdgcn_sched_barrier(0);
}

__global__ __launch_bounds__(512)
void gemm256_proj(const __bf16* __restrict__ Ap, const __bf16* __restrict__ Bp,
                  const float* __restrict__ b0, const float* __restrict__ b1,
                  const float* __restrict__ b2, float scaleQ, __bf16* __restrict__ Cp)
{
    __shared__ __bf16 LA[2][256 * 64];
    __shared__ __bf16 LB[2][256 * 64];

    int bx, by, bz;
    xcd_remap(bx, by, bz);                 // grid (4, 32, 3)
    const int m0 = by * 256, n0 = bx * 256;
    const long z = bz;

    const int tid = threadIdx.x;
    const int wid = tid >> 6, lane = tid & 63;
    const int wM = wid >> 2;               // 0..1 : 128-row half
    const int wn = wid & 3;                // 0..3 : 64-col slice
    const int g = lane >> 4, li = lane & 15;
    const int rl = lane >> 3;              // row within 8-row segment
    const int sg = (lane & 7) ^ rl;        // pre-swizzled 16B slot in global

    const __bf16* Az = Ap + z * 8388608L;
    const __bf16* Bz = Bp + z * 1048576L;

    // wave-partitioned staging: wave w covers segs [w*4, w*4+4) of A and of B
    auto ISSUE = [&](int buf, int k0) {
#pragma unroll
        for (int i = 0; i < 4; i++) {
            const int seg = wid * 4 + i;          // 0..31, rows seg*8..seg*8+7
            const int r = seg * 8 + rl;
            gload16(Az + (long)(m0 + r) * 1024 + k0 + sg * 8, &LA[buf][seg * 512]);
        }
#pragma unroll
        for (int i = 0; i < 4; i++) {
            const int seg = wid * 4 + i;
            const int r = seg * 8 + rl;
            gload16(Bz + (long)(n0 + r) * 1024 + k0 + sg * 8, &LB[buf][seg * 512]);
        }
    };

    f32x4 acc[8][4];
#pragma unroll
    for (int i = 0; i < 8; i++)
#pragma unroll
        for (int j = 0; j < 4; j++)
            acc[i][j] = (f32x4){0.f, 0.f, 0.f, 0.f};
    bf16x8 aF[4][2], bF[2][2];

    const int nt = 16;                     // K = 1024 / BK 64
    ISSUE(0, 0);                           // prologue: tile 0 in flight
    int cur = 0;
    for (int t = 0; t < nt; ++t) {
        // ---- tile boundary: prefetch next tile, counted wait, sync ----
        if (t + 1 < nt) {
            ISSUE(cur ^ 1, (t + 1) * 64);
            __builtin_amdgcn_sched_barrier(0);
            asm volatile("s_waitcnt vmcnt(8)" ::: "memory");   // tile t landed; next 8 fly
        } else {
            __builtin_amdgcn_sched_barrier(0);
            asm volatile("s_waitcnt vmcnt(0)" ::: "memory");   // final tile: drain
        }
        __builtin_amdgcn_sched_barrier(0);
        __builtin_amdgcn_s_barrier();      // all waves: tile t visible in LDS
        __builtin_amdgcn_sched_barrier(0);

        const char* LAb = (const char*)&LA[cur][0];
        const char* LBb = (const char*)&LB[cur][0];
        phase256<0, 0, true,  true >(LAb, LBb, wM, wn, g, li, aF, bF, acc);
        phase256<0, 1, false, true >(LAb, LBb, wM, wn, g, li, aF, bF, acc);
        phase256<1, 1, true,  false>(LAb, LBb, wM, wn, g, li, aF, bF, acc);
        phase256<1, 0, false, true >(LAb, LBb, wM, wn, g, li, aF, bF, acc);
        cur ^= 1;
    }

    // ---- epilogue: C/D layout col = lane&15, row = 4*(lane>>4)+reg ----
    const float scale = (z == 0) ? scaleQ : 1.f;
    const float* bias = z == 0 ? b0 : (z == 1 ? b1 : b2);
    __bf16* C = Cp + z * 8388608L;
#pragma unroll
    for (int fi = 0; fi < 8; fi++) {
#pragma unroll
        for (int fj = 0; fj < 4; fj++) {
            const int row = m0 + wM * 128 + fi * 16 + g * 4;
            const int col = n0 + wn * 64 + fj * 16 + li;
            const float b = bias[col];
#pragma unroll
            for (int jj = 0; jj < 4; jj++)
                C[(long)(row + jj) * 1024 + col] = (__bf16)((acc[fi][fj][jj] + b) * scale);
        }
    }
}

// ================= 128x128 2-phase GEMM (r5-verified) for scores / PV =================
// MODE 1: C f32; causal block skip. MODE 2: C f32; K truncated at m0+BM.
template<int MODE>
__global__ __launch_bounds__(256)
void gemm_bt(const __bf16* __restrict__ Ap, const __bf16* __restrict__ Bp,
             void* __restrict__ Cp, int Kd, int lda, int ldb, int ldc,
             long strideA, long strideB, long strideC)
{
    __shared__ __bf16 smA[2][BM * BKK];
    __shared__ __bf16 smB[2][BN * BKK];

    int bx, by, bz;
    xcd_remap(bx, by, bz);

    const int tid = threadIdx.x;
    const int m0 = by * BM;
    const int n0 = bx * BN;
    if (MODE == 1 && n0 > m0) return;   // fully-masked causal block

    const long z = bz;
    int kEnd = Kd;
    if (MODE == 2) { int lim = m0 + BM; kEnd = lim < Kd ? lim : Kd; }

    const int wid = tid >> 6, lane = tid & 63;
    const int wm = (wid >> 1) * 64, wn = (wid & 1) * 64;
    const int g = lane >> 4, li = lane & 15;
    const int rl = lane >> 3;
    const int sg = (lane & 7) ^ rl;
    const __bf16* Az = Ap + z * strideA;
    const __bf16* Bz = Bp + z * strideB;

    f32x4 acc[4][4];
    for (int i = 0; i < 4; i++)
        for (int j = 0; j < 4; j++)
            acc[i][j] = (f32x4){0.f, 0.f, 0.f, 0.f};

    auto STAGE = [&](int buf, int k0) {
        for (int i = 0; i < 4; i++) {
            const int seg = i * 4 + wid;
            const int r = seg * 8 + rl;
            gload16(Az + (long)(m0 + r) * lda + k0 + sg * 8, &smA[buf][seg * 512]);
            gload16(Bz + (long)(n0 + r) * ldb + k0 + sg * 8, &smB[buf][seg * 512]);
        }
    };

    auto COMPUTE = [&](int buf) {
        for (int kk = 0; kk < 2; kk++) {
            const int slot = kk * 4 + g;
            bf16x8 af[4], bfv[4];
            for (int t = 0; t < 4; t++)
                af[t] = *(const bf16x8*)((const char*)&smA[buf][0] + swz(wm + t * 16 + li, slot));
            for (int t = 0; t < 4; t++)
                bfv[t] = *(const bf16x8*)((const char*)&smB[buf][0] + swz(wn + t * 16 + li, slot));
            for (int tm = 0; tm < 4; tm++)
                for (int tn = 0; tn < 4; tn++)
                    acc[tm][tn] = __builtin_amdgcn_mfma_f32_16x16x32_bf16(
                        af[tm], bfv[tn], acc[tm][tn], 0, 0, 0);
        }
    };

    const int nt = kEnd / BKK;
    STAGE(0, 0);
    __syncthreads();
    int cur = 0;
    for (int t = 0; t < nt - 1; ++t) {
        STAGE(cur ^ 1, (t + 1) * BKK);
        COMPUTE(cur);
        __syncthreads();
        cur ^= 1;
    }
    COMPUTE(cur);

    for (int tm = 0; tm < 4; tm++) {
        for (int tn = 0; tn < 4; tn++) {
            const int row = m0 + wm + tm * 16 + g * 4;
            const int col = n0 + wn + tn * 16 + li;
            float* C = (float*)Cp + z * strideC;
            for (int j = 0; j < 4; j++)
                C[(long)(row + j) * ldc + col] = acc[tm][tn][j];
        }
    }
}

// f32 -> bf16 for 3 same-size tensors; blockIdx.y selects tensor
__global__ __launch_bounds__(256)
void cvt3(const float* __restrict__ s0, const float* __restrict__ s1,
          const float* __restrict__ s2, __bf16* __restrict__ d0,
          __bf16* __restrict__ d1, __bf16* __restrict__ d2, long n)
{
    const int zz = blockIdx.y;
    const float* src = zz == 0 ? s0 : (zz == 1 ? s1 : s2);
    __bf16* dst = zz == 0 ? d0 : (zz == 1 ? d1 : d2);
    long i = ((long)blockIdx.x * 256 + threadIdx.x) * 8;
    const long stride = (long)gridDim.x * 2048;
    for (; i < n; i += stride) {
        float4 a = *(const float4*)(src + i);
        float4 b = *(const float4*)(src + i + 4);
        bf16x8 v;
        v[0] = (__bf16)a.x; v[1] = (__bf16)a.y; v[2] = (__bf16)a.z; v[3] = (__bf16)a.w;
        v[4] = (__bf16)b.x; v[5] = (__bf16)b.y; v[6] = (__bf16)b.z; v[7] = (__bf16)b.w;
        *(bf16x8*)(dst + i) = v;
    }
}

// V [2048][1024] bf16 -> Vt [1024][2048] bf16 (per batch in blockIdx.z)
__global__ __launch_bounds__(256)
void transpose2d(const ushort* __restrict__ V, ushort* __restrict__ Vt)
{
    __shared__ ushort t[64][65];
    const int d0 = blockIdx.x * 64, k0 = blockIdx.y * 64;
    const long nb = blockIdx.z;
    const ushort* Vb = V + nb * 2048 * 1024;
    ushort* Vtb = Vt + nb * 1024 * 2048;

    for (int i = 0; i < 16; i++) {
        int lin = threadIdx.x + 256 * i;
        int r = lin >> 6, c = lin & 63;
        t[r][c] = Vb[(long)(k0 + r) * 1024 + d0 + c];
    }
    __syncthreads();
    for (int i = 0; i < 16; i++) {
        int lin = threadIdx.x + 256 * i;
        int r = lin >> 6, c = lin & 63;
        Vtb[(long)(d0 + r) * 2048 + k0 + c] = t[c][r];
    }
}

// Causal softmax over S[n][q][0..q], writes bf16 P in-place (row stride 4096 elems).
__global__ __launch_bounds__(256)
void softmax_causal(float* __restrict__ S)
{
    const int q = blockIdx.x;
    const long rowoff = (long)blockIdx.y * 2048 + q;
    const float* Srow = S + rowoff * 2048;
    __bf16* Prow = (__bf16*)S + rowoff * 4096;

    const int tid = threadIdx.x;
    const int wid = tid >> 6, lane = tid & 63;

    float v[8];
    float mx = -1e30f;
    for (int i = 0; i < 8; i++) {
        int idx = tid + 256 * i;
        v[i] = (idx <= q) ? Srow[idx] : -1e30f;
        mx = fmaxf(mx, v[i]);
    }
    for (int off = 32; off; off >>= 1) mx = fmaxf(mx, __shfl_xor(mx, off));
    __shared__ float red[8];
    if (lane == 0) red[wid] = mx;
    __syncthreads();
    mx = fmaxf(fmaxf(red[0], red[1]), fmaxf(red[2], red[3]));

    float e[8];
    float s = 0.f;
    for (int i = 0; i < 8; i++) {
        int idx = tid + 256 * i;
        e[i] = (idx <= q) ? __expf(v[i] - mx) : 0.f;
        s += e[i];
    }
    for (int off = 32; off; off >>= 1) s += __shfl_xor(s, off);
    if (lane == 0) red[4 + wid] = s;
    __syncthreads();
    s = red[4] + red[5] + red[6] + red[7];
    const float inv = 1.f / s;

    for (int i = 0; i < 8; i++)
        Prow[tid + 256 * i] = (__bf16)(e[i] * inv);
}

extern "C" void kernel_launch(void* const* d_in, const int* in_sizes, int n_in,
                              void* d_out, int out_size, void* d_ws, size_t ws_size,
                              hipStream_t stream) {
    const float* query = (const float*)d_in[0];
    const float* key   = (const float*)d_in[1];
    const float* value = (const float*)d_in[2];
    // d_in[3] = mask : deterministic causal triu -> applied by index, ignored here
    const float* Wq = (const float*)d_in[4];
    const float* bq = (const float*)d_in[5];
    const float* Wk = (const float*)d_in[6];
    const float* bk = (const float*)d_in[7];
    const float* Wv = (const float*)d_in[8];
    const float* bv = (const float*)d_in[9];
    float* out = (float*)d_out;

    char* ws = (char*)d_ws;
    const long MB = 1L << 20;
    __bf16* QKV = (__bf16*)(ws);             // [3][8192][1024], stride 8M elems
    __bf16* Vp  = QKV + 2 * 8388608L;
    __bf16* Vt  = (__bf16*)(ws + 48 * MB);
    float*  S   = (float*) (ws + 64 * MB);
    __bf16* Xb  = (__bf16*)(ws + 64 * MB);   // overlap, dead before S
    __bf16* Wb  = (__bf16*)(ws + 112 * MB);

    const dim3 blk(256);
    const long nX = 2048L * 1024 * 4;
    const long nW = 1024L * 1024;

    // 0) f32 -> bf16 conversions
    cvt3<<<dim3(1024, 3), blk, 0, stream>>>(query, key, value,
        Xb, Xb + 8388608L, Xb + 2 * 8388608L, nX);
    cvt3<<<dim3(512, 3), blk, 0, stream>>>(Wq, Wk, Wv,
        Wb, Wb + 1048576L, Wb + 2 * 1048576L, nW);

    // 1) merged projections, 256^2 8-phase schedule
    gemm256_proj<<<dim3(4, 32, 3), dim3(512), 0, stream>>>(
        Xb, Wb, bq, bk, bv, 1.f / 32.f, QKV);

    // 2) V -> Vt
    transpose2d<<<dim3(16, 32, 4), blk, 0, stream>>>((const ushort*)Vp, (ushort*)Vt);

    // 3) scores S[n][q][k] = Qs[q].Kp[k]  (causal block skip inside)
    gemm_bt<1><<<dim3(16, 16, 4), blk, 0, stream>>>(QKV, QKV + 8388608L, S,
        1024, 1024, 1024, 2048, 2048L * 1024, 2048L * 1024, 2048L * 2048);

    // 4) causal softmax (in-place S -> P bf16, row stride 4096)
    softmax_causal<<<dim3(2048, 4), blk, 0, stream>>>(S);

    // 5) y = P . V via Vt, causal K truncation
    gemm_bt<2><<<dim3(8, 16, 4), blk, 0, stream>>>((__bf16*)S, Vt, out,
        2048, 4096, 2048, 1024, 2048L * 4096, 1024L * 2048, 2048L * 1024);
}

// Round 7
// 206.940 us; speedup vs baseline: 1.0264x; 1.0264x over previous
//
#include <hip/hip_runtime.h>
#include <hip/hip_bf16.h>

// Self-attention: y = softmax_causal((Xq Wq^T + bq)(Xk Wk^T + bk)^T / 32) (Xv Wv^T + bv)
// N=4, K=2048, M=DQ=DV=1024.
//
// Pipeline (bf16 MFMA, f32 accumulate):
//   0) cvt3 x2        : {query,key,value} and {Wq,Wk,Wv} -> bf16
//   1) gemm256_proj   : merged projections, 256^2 m201-faithful 8-phase schedule:
//                       per K-tile 4 quadrant-phases; HALF-tILE staging interleaved
//                       (A0@p1,B0@p2,B1@p3,A1@p4 -> next buffer), counted vmcnt(4)
//                       at p1/p2/p4 (never 0), ds_reads validated one phase early,
//                       setprio(1) around MFMA clusters (T5).
//   2) transpose2d    : V [k][d] -> Vt [d][k]
//   3) gemm_bt<1>     : S = Qs . Kp^T (f32), causal block skip   (r5-verified 2-phase)
//   4) softmax_causal : causal softmax by index, bf16 P in-place over S
//   5) gemm_bt<2>     : y = P . Vt, K truncated at causal boundary, f32 out
//
// Workspace (128 MiB): QKV bf16 [3][8192][1024] @0; Vt @48M; S f32 @64M
//   (overlap, dead before S: Xb @64M, Wb @112M)

typedef __bf16 bf16x8 __attribute__((ext_vector_type(8)));
typedef float  f32x4  __attribute__((ext_vector_type(4)));

#define BM 128
#define BN 128
#define BKK 64

__device__ __forceinline__ int swz(int row, int slot) {
    return row * 128 + (((slot) ^ (row & 7)) << 4);
}

__device__ __forceinline__ void gload16(const __bf16* g, __bf16* l) {
    __builtin_amdgcn_global_load_lds((const __attribute__((address_space(1))) void*)g,
                                     (__attribute__((address_space(3))) void*)l, 16, 0, 0);
}

// T1: bijective XCD-chunked remap (m204)
__device__ __forceinline__ void xcd_remap(int& bx, int& by, int& bz) {
    const int nx = gridDim.x, ny = gridDim.y;
    const int nwg = nx * ny * gridDim.z;
    const int flat = blockIdx.x + nx * (blockIdx.y + ny * blockIdx.z);
    const int q = nwg >> 3, r = nwg & 7;
    const int xcd = flat & 7, idx = flat >> 3;
    const int l = (xcd < r ? xcd * (q + 1) : r * (q + 1) + (xcd - r) * q) + idx;
    bx = l % nx; by = (l / nx) % ny; bz = l / (nx * ny);
}

#define SBAR()  do { __builtin_amdgcn_s_barrier(); __builtin_amdgcn_sched_barrier(0); } while (0)
#define VMCNT4() do { __builtin_amdgcn_sched_barrier(0); \
                      asm volatile("s_waitcnt vmcnt(4)" ::: "memory"); \
                      __builtin_amdgcn_sched_barrier(0); } while (0)

// ======================= 256x256 8-phase projection GEMM =======================
// C[z][8192][1024] = X[z][8192][1024] . W[z][1024][1024]^T (+bias[z], z==0 *1/32)
__global__ __launch_bounds__(512)
void gemm256_proj(const __bf16* __restrict__ Ap, const __bf16* __restrict__ Bp,
                  const float* __restrict__ b0, const float* __restrict__ b1,
                  const float* __restrict__ b2, float scaleQ, __bf16* __restrict__ Cp)
{
    __shared__ __bf16 LA[2][256 * 64];
    __shared__ __bf16 LB[2][256 * 64];

    int bx, by, bz;
    xcd_remap(bx, by, bz);                 // grid (4, 32, 3)
    const int m0 = by * 256, n0 = bx * 256;
    const long z = bz;

    const int tid = threadIdx.x;
    const int wid = tid >> 6, lane = tid & 63;
    const int wr = wid >> 1;               // 0..3 : 32-row slice within quadrant
    const int wc = wid & 1;                // 0..1 : 64-col slice within quadrant
    const int g = lane >> 4, li = lane & 15;
    const int rl = lane >> 3;              // row within 8-row segment
    const int sg = (lane & 7) ^ rl;        // pre-swizzled 16B slot in global

    const __bf16* Az = Ap + z * 8388608L;
    const __bf16* Bz = Bp + z * 1048576L;

    // halves: 0=A rows[0,128)  1=B rows[0,128)  2=B rows[128,256)  3=A rows[128,256)
    // each half: 16 segs of 8 rows; wave w stages segs {2w, 2w+1} (2 gloads/thread)
    auto ISSUE_HALF = [&](int buf, int k0, int h) {
        const bool isA = (h == 0 || h == 3);
        const int rowoff = (h == 0 || h == 1) ? 0 : 128;
        const __bf16* src = isA ? Az : Bz;
        const int base0 = isA ? m0 : n0;
        __bf16* dst = (isA ? &LA[buf][0] : &LB[buf][0]) + rowoff * 64;
#pragma unroll
        for (int i = 0; i < 2; i++) {
            const int seg = wid * 2 + i;               // 0..15
            const int r = rowoff + seg * 8 + rl;
            gload16(src + (long)(base0 + r) * 1024 + k0 + sg * 8, dst + seg * 512);
        }
    };

    bf16x8 aF[2][2];        // [fi][kk], current A-half's frags (rows wr*32+fi*16)
    bf16x8 bF[2][4][2];     // [qn][fj][kk], both B-halves' frags persist
    f32x4 acc[4][2][4];     // [qm*2+qn][fi][fj]
#pragma unroll
    for (int q2 = 0; q2 < 4; q2++)
#pragma unroll
        for (int fi = 0; fi < 2; fi++)
#pragma unroll
            for (int fj = 0; fj < 4; fj++)
                acc[q2][fi][fj] = (f32x4){0.f, 0.f, 0.f, 0.f};

    auto DSREAD_A = [&](int buf, int qm) {
#pragma unroll
        for (int fi = 0; fi < 2; fi++)
#pragma unroll
            for (int kk = 0; kk < 2; kk++)
                aF[fi][kk] = *(const bf16x8*)((const char*)&LA[buf][0] +
                    swz(qm * 128 + wr * 32 + fi * 16 + li, kk * 4 + g));
    };
    auto DSREAD_B = [&](int buf, int qn) {
#pragma unroll
        for (int fj = 0; fj < 4; fj++)
#pragma unroll
            for (int kk = 0; kk < 2; kk++)
                bF[qn][fj][kk] = *(const bf16x8*)((const char*)&LB[buf][0] +
                    swz(qn * 128 + wc * 64 + fj * 16 + li, kk * 4 + g));
    };
    auto MFMA16 = [&](int qm, int qn) {
        __builtin_amdgcn_s_setprio(1);
#pragma unroll
        for (int kk = 0; kk < 2; kk++)
#pragma unroll
            for (int fi = 0; fi < 2; fi++)
#pragma unroll
                for (int fj = 0; fj < 4; fj++)
                    acc[qm * 2 + qn][fi][fj] = __builtin_amdgcn_mfma_f32_16x16x32_bf16(
                        aF[fi][kk], bF[qn][fj][kk], acc[qm * 2 + qn][fi][fj], 0, 0, 0);
        __builtin_amdgcn_s_setprio(0);
    };

    const int nt = 16;                     // K = 1024 / 64
    // prologue: all 4 halves of tile 0; wait A0,B0 (2 newest halves may fly)
    ISSUE_HALF(0, 0, 0); ISSUE_HALF(0, 0, 1); ISSUE_HALF(0, 0, 2); ISSUE_HALF(0, 0, 3);
    VMCNT4();
    SBAR();

    int cur = 0;
    for (int t = 0; t < nt; ++t) {
        const int nxt = cur ^ 1;
        const int k0n = (t + 1 < nt) ? (t + 1) * 64 : 0;   // wrap: uniform vmcnt ledger

        // ---- p1: quad (0,0); stage A0(next); wait -> B1(cur) done ----
        DSREAD_A(cur, 0); DSREAD_B(cur, 0);
        ISSUE_HALF(nxt, k0n, 0);
        VMCNT4();
        SBAR();
        MFMA16(0, 0);
        SBAR();
        // ---- p2: quad (0,1); stage B0(next); wait -> A1(cur) done ----
        DSREAD_B(cur, 1);
        ISSUE_HALF(nxt, k0n, 1);
        VMCNT4();
        SBAR();
        MFMA16(0, 1);
        SBAR();
        // ---- p3: quad (1,1); stage B1(next); no wait needed ----
        DSREAD_A(cur, 1);
        ISSUE_HALF(nxt, k0n, 2);
        SBAR();
        MFMA16(1, 1);
        SBAR();
        // ---- p4: quad (1,0) (reuses aF, bF[0]); stage A1(next); wait -> A0,B0(next) done ----
        ISSUE_HALF(nxt, k0n, 3);
        VMCNT4();
        SBAR();
        MFMA16(1, 0);
        SBAR();
        cur = nxt;
    }
    __builtin_amdgcn_sched_barrier(0);
    asm volatile("s_waitcnt vmcnt(0)" ::: "memory");   // drain wrap-issued loads

    // ---- epilogue: C/D layout col = lane&15, row = 4*(lane>>4)+reg ----
    const float scale = (z == 0) ? scaleQ : 1.f;
    const float* bias = z == 0 ? b0 : (z == 1 ? b1 : b2);
    __bf16* C = Cp + z * 8388608L;
#pragma unroll
    for (int qm = 0; qm < 2; qm++)
#pragma unroll
        for (int qn = 0; qn < 2; qn++)
#pragma unroll
            for (int fi = 0; fi < 2; fi++)
#pragma unroll
                for (int fj = 0; fj < 4; fj++) {
                    const int row = m0 + qm * 128 + wr * 32 + fi * 16 + g * 4;
                    const int col = n0 + qn * 128 + wc * 64 + fj * 16 + li;
                    const float b = bias[col];
#pragma unroll
                    for (int jj = 0; jj < 4; jj++)
                        C[(long)(row + jj) * 1024 + col] =
                            (__bf16)((acc[qm * 2 + qn][fi][fj][jj] + b) * scale);
                }
}

// ================= 128x128 2-phase GEMM (r5-verified) for scores / PV =================
// MODE 1: C f32; causal block skip. MODE 2: C f32; K truncated at m0+BM.
template<int MODE>
__global__ __launch_bounds__(256)
void gemm_bt(const __bf16* __restrict__ Ap, const __bf16* __restrict__ Bp,
             void* __restrict__ Cp, int Kd, int lda, int ldb, int ldc,
             long strideA, long strideB, long strideC)
{
    __shared__ __bf16 smA[2][BM * BKK];
    __shared__ __bf16 smB[2][BN * BKK];

    int bx, by, bz;
    xcd_remap(bx, by, bz);

    const int tid = threadIdx.x;
    const int m0 = by * BM;
    const int n0 = bx * BN;
    if (MODE == 1 && n0 > m0) return;   // fully-masked causal block

    const long z = bz;
    int kEnd = Kd;
    if (MODE == 2) { int lim = m0 + BM; kEnd = lim < Kd ? lim : Kd; }

    const int wid = tid >> 6, lane = tid & 63;
    const int wm = (wid >> 1) * 64, wn = (wid & 1) * 64;
    const int g = lane >> 4, li = lane & 15;
    const int rl = lane >> 3;
    const int sg = (lane & 7) ^ rl;
    const __bf16* Az = Ap + z * strideA;
    const __bf16* Bz = Bp + z * strideB;

    f32x4 acc[4][4];
    for (int i = 0; i < 4; i++)
        for (int j = 0; j < 4; j++)
            acc[i][j] = (f32x4){0.f, 0.f, 0.f, 0.f};

    auto STAGE = [&](int buf, int k0) {
        for (int i = 0; i < 4; i++) {
            const int seg = i * 4 + wid;
            const int r = seg * 8 + rl;
            gload16(Az + (long)(m0 + r) * lda + k0 + sg * 8, &smA[buf][seg * 512]);
            gload16(Bz + (long)(n0 + r) * ldb + k0 + sg * 8, &smB[buf][seg * 512]);
        }
    };

    auto COMPUTE = [&](int buf) {
        for (int kk = 0; kk < 2; kk++) {
            const int slot = kk * 4 + g;
            bf16x8 af[4], bfv[4];
            for (int t = 0; t < 4; t++)
                af[t] = *(const bf16x8*)((const char*)&smA[buf][0] + swz(wm + t * 16 + li, slot));
            for (int t = 0; t < 4; t++)
                bfv[t] = *(const bf16x8*)((const char*)&smB[buf][0] + swz(wn + t * 16 + li, slot));
            for (int tm = 0; tm < 4; tm++)
                for (int tn = 0; tn < 4; tn++)
                    acc[tm][tn] = __builtin_amdgcn_mfma_f32_16x16x32_bf16(
                        af[tm], bfv[tn], acc[tm][tn], 0, 0, 0);
        }
    };

    const int nt = kEnd / BKK;
    STAGE(0, 0);
    __syncthreads();
    int cur = 0;
    for (int t = 0; t < nt - 1; ++t) {
        STAGE(cur ^ 1, (t + 1) * BKK);
        COMPUTE(cur);
        __syncthreads();
        cur ^= 1;
    }
    COMPUTE(cur);

    for (int tm = 0; tm < 4; tm++) {
        for (int tn = 0; tn < 4; tn++) {
            const int row = m0 + wm + tm * 16 + g * 4;
            const int col = n0 + wn + tn * 16 + li;
            float* C = (float*)Cp + z * strideC;
            for (int j = 0; j < 4; j++)
                C[(long)(row + j) * ldc + col] = acc[tm][tn][j];
        }
    }
}

// f32 -> bf16 for 3 same-size tensors; blockIdx.y selects tensor
__global__ __launch_bounds__(256)
void cvt3(const float* __restrict__ s0, const float* __restrict__ s1,
          const float* __restrict__ s2, __bf16* __restrict__ d0,
          __bf16* __restrict__ d1, __bf16* __restrict__ d2, long n)
{
    const int zz = blockIdx.y;
    const float* src = zz == 0 ? s0 : (zz == 1 ? s1 : s2);
    __bf16* dst = zz == 0 ? d0 : (zz == 1 ? d1 : d2);
    long i = ((long)blockIdx.x * 256 + threadIdx.x) * 8;
    const long stride = (long)gridDim.x * 2048;
    for (; i < n; i += stride) {
        float4 a = *(const float4*)(src + i);
        float4 b = *(const float4*)(src + i + 4);
        bf16x8 v;
        v[0] = (__bf16)a.x; v[1] = (__bf16)a.y; v[2] = (__bf16)a.z; v[3] = (__bf16)a.w;
        v[4] = (__bf16)b.x; v[5] = (__bf16)b.y; v[6] = (__bf16)b.z; v[7] = (__bf16)b.w;
        *(bf16x8*)(dst + i) = v;
    }
}

// V [2048][1024] bf16 -> Vt [1024][2048] bf16 (per batch in blockIdx.z)
__global__ __launch_bounds__(256)
void transpose2d(const ushort* __restrict__ V, ushort* __restrict__ Vt)
{
    __shared__ ushort t[64][65];
    const int d0 = blockIdx.x * 64, k0 = blockIdx.y * 64;
    const long nb = blockIdx.z;
    const ushort* Vb = V + nb * 2048 * 1024;
    ushort* Vtb = Vt + nb * 1024 * 2048;

    for (int i = 0; i < 16; i++) {
        int lin = threadIdx.x + 256 * i;
        int r = lin >> 6, c = lin & 63;
        t[r][c] = Vb[(long)(k0 + r) * 1024 + d0 + c];
    }
    __syncthreads();
    for (int i = 0; i < 16; i++) {
        int lin = threadIdx.x + 256 * i;
        int r = lin >> 6, c = lin & 63;
        Vtb[(long)(d0 + r) * 2048 + k0 + c] = t[c][r];
    }
}

// Causal softmax over S[n][q][0..q], writes bf16 P in-place (row stride 4096 elems).
__global__ __launch_bounds__(256)
void softmax_causal(float* __restrict__ S)
{
    const int q = blockIdx.x;
    const long rowoff = (long)blockIdx.y * 2048 + q;
    const float* Srow = S + rowoff * 2048;
    __bf16* Prow = (__bf16*)S + rowoff * 4096;

    const int tid = threadIdx.x;
    const int wid = tid >> 6, lane = tid & 63;

    float v[8];
    float mx = -1e30f;
    for (int i = 0; i < 8; i++) {
        int idx = tid + 256 * i;
        v[i] = (idx <= q) ? Srow[idx] : -1e30f;
        mx = fmaxf(mx, v[i]);
    }
    for (int off = 32; off; off >>= 1) mx = fmaxf(mx, __shfl_xor(mx, off));
    __shared__ float red[8];
    if (lane == 0) red[wid] = mx;
    __syncthreads();
    mx = fmaxf(fmaxf(red[0], red[1]), fmaxf(red[2], red[3]));

    float e[8];
    float s = 0.f;
    for (int i = 0; i < 8; i++) {
        int idx = tid + 256 * i;
        e[i] = (idx <= q) ? __expf(v[i] - mx) : 0.f;
        s += e[i];
    }
    for (int off = 32; off; off >>= 1) s += __shfl_xor(s, off);
    if (lane == 0) red[4 + wid] = s;
    __syncthreads();
    s = red[4] + red[5] + red[6] + red[7];
    const float inv = 1.f / s;

    for (int i = 0; i < 8; i++)
        Prow[tid + 256 * i] = (__bf16)(e[i] * inv);
}

extern "C" void kernel_launch(void* const* d_in, const int* in_sizes, int n_in,
                              void* d_out, int out_size, void* d_ws, size_t ws_size,
                              hipStream_t stream) {
    const float* query = (const float*)d_in[0];
    const float* key   = (const float*)d_in[1];
    const float* value = (const float*)d_in[2];
    // d_in[3] = mask : deterministic causal triu -> applied by index, ignored here
    const float* Wq = (const float*)d_in[4];
    const float* bq = (const float*)d_in[5];
    const float* Wk = (const float*)d_in[6];
    const float* bk = (const float*)d_in[7];
    const float* Wv = (const float*)d_in[8];
    const float* bv = (const float*)d_in[9];
    float* out = (float*)d_out;

    char* ws = (char*)d_ws;
    const long MB = 1L << 20;
    __bf16* QKV = (__bf16*)(ws);             // [3][8192][1024], stride 8M elems
    __bf16* Vp  = QKV + 2 * 8388608L;
    __bf16* Vt  = (__bf16*)(ws + 48 * MB);
    float*  S   = (float*) (ws + 64 * MB);
    __bf16* Xb  = (__bf16*)(ws + 64 * MB);   // overlap, dead before S
    __bf16* Wb  = (__bf16*)(ws + 112 * MB);

    const dim3 blk(256);
    const long nX = 2048L * 1024 * 4;
    const long nW = 1024L * 1024;

    // 0) f32 -> bf16 conversions
    cvt3<<<dim3(1024, 3), blk, 0, stream>>>(query, key, value,
        Xb, Xb + 8388608L, Xb + 2 * 8388608L, nX);
    cvt3<<<dim3(512, 3), blk, 0, stream>>>(Wq, Wk, Wv,
        Wb, Wb + 1048576L, Wb + 2 * 1048576L, nW);

    // 1) merged projections, 256^2 8-phase (half-tile interleaved staging)
    gemm256_proj<<<dim3(4, 32, 3), dim3(512), 0, stream>>>(
        Xb, Wb, bq, bk, bv, 1.f / 32.f, QKV);

    // 2) V -> Vt
    transpose2d<<<dim3(16, 32, 4), blk, 0, stream>>>((const ushort*)Vp, (ushort*)Vt);

    // 3) scores S[n][q][k] = Qs[q].Kp[k]  (causal block skip inside)
    gemm_bt<1><<<dim3(16, 16, 4), blk, 0, stream>>>(QKV, QKV + 8388608L, S,
        1024, 1024, 1024, 2048, 2048L * 1024, 2048L * 1024, 2048L * 2048);

    // 4) causal softmax (in-place S -> P bf16, row stride 4096)
    softmax_causal<<<dim3(2048, 4), blk, 0, stream>>>(S);

    // 5) y = P . V via Vt, causal K truncation
    gemm_bt<2><<<dim3(8, 16, 4), blk, 0, stream>>>((__bf16*)S, Vt, out,
        2048, 4096, 2048, 1024, 2048L * 4096, 1024L * 2048, 2048L * 1024);
}

// Round 8
// 183.848 us; speedup vs baseline: 1.1553x; 1.1256x over previous
//
#include <hip/hip_runtime.h>
#include <hip/hip_bf16.h>

// Self-attention: y = softmax_causal((Xq Wq^T + bq)(Xk Wk^T + bk)^T / 32) (Xv Wv^T + bv)
// N=4, K=2048, M=DQ=DV=1024.
//
// Pipeline (bf16 MFMA, f32 accumulate):
//   0) cvt3          : {Wq,Wk,Wv} -> bf16 (12 MB, tiny)
//   1) gemm_proj     : merged projections, r5-verified 128^2 2-phase dbuf structure.
//                      A (X) read DIRECTLY as f32, converted during reg-staging
//                      (issue loads early / ds_write late, T14); B (W) via
//                      global_load_lds w=16 pre-swizzled source. z==0/1 write Q/K
//                      (+bias, Q scaled 1/32); z==2 writes V TRANSPOSED to Vt via
//                      LDS bounce (no Vp, no separate transpose kernel).
//   2) gemm_bt<1>    : S = Qs . Kp^T (f32), causal block skip
//   3) softmax_causal: causal softmax by index, bf16 P in-place over S (row stride
//                      4096), writes only k <= (q|127)
//   4) gemm_bt<2>    : y = P . Vt, K truncated at causal boundary, f32 out
//
// Workspace (128 MiB): QKV bf16 [3][8192][1024] @0 (z=2 slab unused); Vt @48M;
//   S f32 [4][2048][2048] @64M (aliased per-row by P bf16, row stride 4096);
//   Wb bf16 [3][1024][1024] @112M (overlap region, dead before S written)

typedef __bf16 bf16x8 __attribute__((ext_vector_type(8)));
typedef float  f32x4  __attribute__((ext_vector_type(4)));

#define BM 128
#define BN 128
#define BKK 64

// byte offset into a [rows][64] bf16 LDS tile, 16B slots XOR-swizzled by row
__device__ __forceinline__ int swz(int row, int slot) {
    return row * 128 + (((slot) ^ (row & 7)) << 4);
}

__device__ __forceinline__ void gload16(const __bf16* g, __bf16* l) {
    __builtin_amdgcn_global_load_lds((const __attribute__((address_space(1))) void*)g,
                                     (__attribute__((address_space(3))) void*)l, 16, 0, 0);
}

// T1: bijective XCD-chunked remap (m204)
__device__ __forceinline__ void xcd_remap(int& bx, int& by, int& bz) {
    const int nx = gridDim.x, ny = gridDim.y;
    const int nwg = nx * ny * gridDim.z;
    const int flat = blockIdx.x + nx * (blockIdx.y + ny * blockIdx.z);
    const int q = nwg >> 3, r = nwg & 7;
    const int xcd = flat & 7, idx = flat >> 3;
    const int l = (xcd < r ? xcd * (q + 1) : r * (q + 1) + (xcd - r) * q) + idx;
    bx = l % nx; by = (l / nx) % ny; bz = l / (nx * ny);
}

// ======================= merged projection GEMM (f32 A, fused cvt) =======================
// QKV[z][8192][1024] = X_z[8192][1024](f32) . W[z][1024][1024]^T (+bias[z]); z0 *= 1/32
// z==2: output written transposed to Vt[4][1024][2048] instead.
__global__ __launch_bounds__(256)
void gemm_proj(const float* __restrict__ xq, const float* __restrict__ xk,
               const float* __restrict__ xv, const __bf16* __restrict__ Wb,
               const float* __restrict__ b0, const float* __restrict__ b1,
               const float* __restrict__ b2, float scaleQ,
               __bf16* __restrict__ QKV, __bf16* __restrict__ Vt)
{
    __shared__ char smem[65536];
    __bf16* smA = (__bf16*)smem;            // [2][128*64]
    __bf16* smB = (__bf16*)(smem + 32768);  // [2][128*64]

    int bx, by, bz;
    xcd_remap(bx, by, bz);                  // grid (8, 64, 3)
    const int m0 = by * BM, n0 = bx * BN;
    const int z = bz;
    const float* X = z == 0 ? xq : (z == 1 ? xk : xv);
    const __bf16* Bz = Wb + (long)z * 1048576L;

    const int tid = threadIdx.x;
    const int wid = tid >> 6, lane = tid & 63;
    const int wm = (wid >> 1) * 64, wn = (wid & 1) * 64;  // 2x2 waves, 64x64 each
    const int g = lane >> 4, li = lane & 15;
    const int rl = lane >> 3;               // row within 8-row segment
    const int sl = lane & 7;                // linear 16B slot (A reg-stage path)
    const int sg = sl ^ rl;                 // pre-swizzled slot (B gload_lds path)

    float4 aReg[4][2];
    auto ISSUE_A = [&](int k0) {            // 8x global_load_dwordx4 (f32), async
#pragma unroll
        for (int i = 0; i < 4; i++) {
            const int r = (i * 4 + wid) * 8 + rl;
            const float* p = X + (long)(m0 + r) * 1024 + k0 + sl * 8;
            aReg[i][0] = *(const float4*)p;
            aReg[i][1] = *(const float4*)(p + 4);
        }
    };
    auto WRITE_A = [&](int buf) {           // cvt + swizzled ds_write_b128
        char* base = (char*)(smA + buf * 8192);
#pragma unroll
        for (int i = 0; i < 4; i++) {
            const int r = (i * 4 + wid) * 8 + rl;
            bf16x8 v;
            v[0] = (__bf16)aReg[i][0].x; v[1] = (__bf16)aReg[i][0].y;
            v[2] = (__bf16)aReg[i][0].z; v[3] = (__bf16)aReg[i][0].w;
            v[4] = (__bf16)aReg[i][1].x; v[5] = (__bf16)aReg[i][1].y;
            v[6] = (__bf16)aReg[i][1].z; v[7] = (__bf16)aReg[i][1].w;
            *(bf16x8*)(base + swz(r, sl)) = v;
        }
    };
    auto STAGE_B = [&](int buf, int k0) {   // async global->LDS, pre-swizzled source
#pragma unroll
        for (int i = 0; i < 4; i++) {
            const int seg = i * 4 + wid;
            const int r = seg * 8 + rl;
            gload16(Bz + (long)(n0 + r) * 1024 + k0 + sg * 8, smB + buf * 8192 + seg * 512);
        }
    };

    f32x4 acc[4][4];
#pragma unroll
    for (int i = 0; i < 4; i++)
#pragma unroll
        for (int j = 0; j < 4; j++)
            acc[i][j] = (f32x4){0.f, 0.f, 0.f, 0.f};

    auto COMPUTE = [&](int buf) {
        const char* bA = (const char*)(smA + buf * 8192);
        const char* bB = (const char*)(smB + buf * 8192);
#pragma unroll
        for (int kk = 0; kk < 2; kk++) {
            const int slot = kk * 4 + g;
            bf16x8 af[4], bfv[4];
#pragma unroll
            for (int t = 0; t < 4; t++)
                af[t] = *(const bf16x8*)(bA + swz(wm + t * 16 + li, slot));
#pragma unroll
            for (int t = 0; t < 4; t++)
                bfv[t] = *(const bf16x8*)(bB + swz(wn + t * 16 + li, slot));
#pragma unroll
            for (int tm = 0; tm < 4; tm++)
#pragma unroll
                for (int tn = 0; tn < 4; tn++)
                    acc[tm][tn] = __builtin_amdgcn_mfma_f32_16x16x32_bf16(
                        af[tm], bfv[tn], acc[tm][tn], 0, 0, 0);
        }
    };

    const int nt = 16;                      // K = 1024 / 64
    ISSUE_A(0); STAGE_B(0, 0); WRITE_A(0);
    __syncthreads();
    int cur = 0;
    for (int t = 0; t < nt - 1; ++t) {
        ISSUE_A((t + 1) * BKK);             // f32 loads fly under COMPUTE
        STAGE_B(cur ^ 1, (t + 1) * BKK);    // gload_lds flies under COMPUTE
        COMPUTE(cur);
        WRITE_A(cur ^ 1);                   // waits only on aReg loads
        __syncthreads();
        cur ^= 1;
    }
    COMPUTE(cur);

    // ---- epilogue: C/D layout col = lane&15, row = 4*(lane>>4)+reg ----
    if (z < 2) {
        const float scale = (z == 0) ? scaleQ : 1.f;
        const float* bias = (z == 0) ? b0 : b1;
        __bf16* C = QKV + (long)z * 8388608L;
#pragma unroll
        for (int tm = 0; tm < 4; tm++)
#pragma unroll
            for (int tn = 0; tn < 4; tn++) {
                const int row = m0 + wm + tm * 16 + g * 4;
                const int col = n0 + wn + tn * 16 + li;
                const float b = bias[col];
#pragma unroll
                for (int j = 0; j < 4; j++)
                    C[(long)(row + j) * 1024 + col] = (__bf16)((acc[tm][tn][j] + b) * scale);
            }
    } else {
        // V: bias-add then write TRANSPOSED to Vt via padded LDS bounce
        __syncthreads();                    // done reading smA/smB; reuse as T[128][136]
        __bf16* T = (__bf16*)smem;
#pragma unroll
        for (int tm = 0; tm < 4; tm++)
#pragma unroll
            for (int tn = 0; tn < 4; tn++) {
                const int rowl = wm + tm * 16 + g * 4;      // k-local
                const int coll = wn + tn * 16 + li;         // d-local
                const float b = b2[n0 + coll];
#pragma unroll
                for (int j = 0; j < 4; j++)
                    T[coll * 136 + rowl + j] = (__bf16)(acc[tm][tn][j] + b);
            }
        __syncthreads();
        const long nb = m0 >> 11;           // batch index
        const int kbase = m0 & 2047;
        __bf16* Vtb = Vt + nb * 2097152L;   // [1024][2048] per batch
#pragma unroll
        for (int it = 0; it < 8; it++) {
            const int lin = tid + 256 * it;  // 0..2047
            const int c = lin >> 4;          // d-local 0..127
            const int r0 = (lin & 15) * 8;   // k-local 0..120
            bf16x8 v = *(const bf16x8*)(T + c * 136 + r0);
            *(bf16x8*)(Vtb + (long)(n0 + c) * 2048 + kbase + r0) = v;
        }
    }
}

// ================= 128x128 2-phase GEMM (r5-verified) for scores / PV =================
// MODE 1: C f32; causal block skip. MODE 2: C f32; K truncated at m0+BM.
template<int MODE>
__global__ __launch_bounds__(256)
void gemm_bt(const __bf16* __restrict__ Ap, const __bf16* __restrict__ Bp,
             void* __restrict__ Cp, int Kd, int lda, int ldb, int ldc,
             long strideA, long strideB, long strideC)
{
    __shared__ __bf16 smA[2][BM * BKK];
    __shared__ __bf16 smB[2][BN * BKK];

    int bx, by, bz;
    xcd_remap(bx, by, bz);

    const int tid = threadIdx.x;
    const int m0 = by * BM;
    const int n0 = bx * BN;
    if (MODE == 1 && n0 > m0) return;   // fully-masked causal block

    const long z = bz;
    int kEnd = Kd;
    if (MODE == 2) { int lim = m0 + BM; kEnd = lim < Kd ? lim : Kd; }

    const int wid = tid >> 6, lane = tid & 63;
    const int wm = (wid >> 1) * 64, wn = (wid & 1) * 64;
    const int g = lane >> 4, li = lane & 15;
    const int rl = lane >> 3;
    const int sg = (lane & 7) ^ rl;
    const __bf16* Az = Ap + z * strideA;
    const __bf16* Bz = Bp + z * strideB;

    f32x4 acc[4][4];
    for (int i = 0; i < 4; i++)
        for (int j = 0; j < 4; j++)
            acc[i][j] = (f32x4){0.f, 0.f, 0.f, 0.f};

    auto STAGE = [&](int buf, int k0) {
        for (int i = 0; i < 4; i++) {
            const int seg = i * 4 + wid;
            const int r = seg * 8 + rl;
            gload16(Az + (long)(m0 + r) * lda + k0 + sg * 8, &smA[buf][seg * 512]);
            gload16(Bz + (long)(n0 + r) * ldb + k0 + sg * 8, &smB[buf][seg * 512]);
        }
    };

    auto COMPUTE = [&](int buf) {
        for (int kk = 0; kk < 2; kk++) {
            const int slot = kk * 4 + g;
            bf16x8 af[4], bfv[4];
            for (int t = 0; t < 4; t++)
                af[t] = *(const bf16x8*)((const char*)&smA[buf][0] + swz(wm + t * 16 + li, slot));
            for (int t = 0; t < 4; t++)
                bfv[t] = *(const bf16x8*)((const char*)&smB[buf][0] + swz(wn + t * 16 + li, slot));
            for (int tm = 0; tm < 4; tm++)
                for (int tn = 0; tn < 4; tn++)
                    acc[tm][tn] = __builtin_amdgcn_mfma_f32_16x16x32_bf16(
                        af[tm], bfv[tn], acc[tm][tn], 0, 0, 0);
        }
    };

    const int nt = kEnd / BKK;
    STAGE(0, 0);
    __syncthreads();
    int cur = 0;
    for (int t = 0; t < nt - 1; ++t) {
        STAGE(cur ^ 1, (t + 1) * BKK);
        COMPUTE(cur);
        __syncthreads();
        cur ^= 1;
    }
    COMPUTE(cur);

    for (int tm = 0; tm < 4; tm++) {
        for (int tn = 0; tn < 4; tn++) {
            const int row = m0 + wm + tm * 16 + g * 4;
            const int col = n0 + wn + tn * 16 + li;
            float* C = (float*)Cp + z * strideC;
            for (int j = 0; j < 4; j++)
                C[(long)(row + j) * ldc + col] = acc[tm][tn][j];
        }
    }
}

// f32 -> bf16 for 3 same-size tensors; blockIdx.y selects tensor
__global__ __launch_bounds__(256)
void cvt3(const float* __restrict__ s0, const float* __restrict__ s1,
          const float* __restrict__ s2, __bf16* __restrict__ d0,
          __bf16* __restrict__ d1, __bf16* __restrict__ d2, long n)
{
    const int zz = blockIdx.y;
    const float* src = zz == 0 ? s0 : (zz == 1 ? s1 : s2);
    __bf16* dst = zz == 0 ? d0 : (zz == 1 ? d1 : d2);
    long i = ((long)blockIdx.x * 256 + threadIdx.x) * 8;
    const long stride = (long)gridDim.x * 2048;
    for (; i < n; i += stride) {
        float4 a = *(const float4*)(src + i);
        float4 b = *(const float4*)(src + i + 4);
        bf16x8 v;
        v[0] = (__bf16)a.x; v[1] = (__bf16)a.y; v[2] = (__bf16)a.z; v[3] = (__bf16)a.w;
        v[4] = (__bf16)b.x; v[5] = (__bf16)b.y; v[6] = (__bf16)b.z; v[7] = (__bf16)b.w;
        *(bf16x8*)(dst + i) = v;
    }
}

// Causal softmax over S[n][q][0..q], bf16 P in-place (row stride 4096 elems).
// Writes only k <= (q|127): PV's causal K-truncation never reads beyond.
__global__ __launch_bounds__(256)
void softmax_causal(float* __restrict__ S)
{
    const int q = blockIdx.x;
    const long rowoff = (long)blockIdx.y * 2048 + q;
    const float* Srow = S + rowoff * 2048;
    __bf16* Prow = (__bf16*)S + rowoff * 4096;

    const int tid = threadIdx.x;
    const int wid = tid >> 6, lane = tid & 63;

    float v[8];
    float mx = -1e30f;
    for (int i = 0; i < 8; i++) {
        int idx = tid + 256 * i;
        v[i] = (idx <= q) ? Srow[idx] : -1e30f;
        mx = fmaxf(mx, v[i]);
    }
    for (int off = 32; off; off >>= 1) mx = fmaxf(mx, __shfl_xor(mx, off));
    __shared__ float red[8];
    if (lane == 0) red[wid] = mx;
    __syncthreads();
    mx = fmaxf(fmaxf(red[0], red[1]), fmaxf(red[2], red[3]));

    float e[8];
    float s = 0.f;
    for (int i = 0; i < 8; i++) {
        int idx = tid + 256 * i;
        e[i] = (idx <= q) ? __expf(v[i] - mx) : 0.f;
        s += e[i];
    }
    for (int off = 32; off; off >>= 1) s += __shfl_xor(s, off);
    if (lane == 0) red[4 + wid] = s;
    __syncthreads();           // all Srow reads done before alias writes
    s = red[4] + red[5] + red[6] + red[7];
    const float inv = 1.f / s;

    const int qc = q | 127;
    for (int i = 0; i < 8; i++) {
        int idx = tid + 256 * i;
        if (idx <= qc) Prow[idx] = (__bf16)(e[i] * inv);
    }
}

extern "C" void kernel_launch(void* const* d_in, const int* in_sizes, int n_in,
                              void* d_out, int out_size, void* d_ws, size_t ws_size,
                              hipStream_t stream) {
    const float* query = (const float*)d_in[0];
    const float* key   = (const float*)d_in[1];
    const float* value = (const float*)d_in[2];
    // d_in[3] = mask : deterministic causal triu -> applied by index, ignored here
    const float* Wq = (const float*)d_in[4];
    const float* bq = (const float*)d_in[5];
    const float* Wk = (const float*)d_in[6];
    const float* bk = (const float*)d_in[7];
    const float* Wv = (const float*)d_in[8];
    const float* bv = (const float*)d_in[9];
    float* out = (float*)d_out;

    char* ws = (char*)d_ws;
    const long MB = 1L << 20;
    __bf16* QKV = (__bf16*)(ws);             // [3][8192][1024] (z=2 slab unused)
    __bf16* Vt  = (__bf16*)(ws + 48 * MB);   // [4][1024][2048]
    float*  S   = (float*) (ws + 64 * MB);   // [4][2048][2048]
    __bf16* Wb  = (__bf16*)(ws + 112 * MB);  // [3][1024][1024], dead before S written

    const dim3 blk(256);
    const long nW = 1024L * 1024;

    // 0) W f32 -> bf16 (12 MB total)
    cvt3<<<dim3(512, 3), blk, 0, stream>>>(Wq, Wk, Wv,
        Wb, Wb + 1048576L, Wb + 2 * 1048576L, nW);

    // 1) merged projections (fused X cvt; z==2 writes Vt transposed)
    gemm_proj<<<dim3(8, 64, 3), blk, 0, stream>>>(
        query, key, value, Wb, bq, bk, bv, 1.f / 32.f, QKV, Vt);

    // 2) scores S[n][q][k] = Qs[q].Kp[k]  (causal block skip inside)
    gemm_bt<1><<<dim3(16, 16, 4), blk, 0, stream>>>(QKV, QKV + 8388608L, S,
        1024, 1024, 1024, 2048, 2048L * 1024, 2048L * 1024, 2048L * 2048);

    // 3) causal softmax (in-place S -> P bf16, row stride 4096)
    softmax_causal<<<dim3(2048, 4), blk, 0, stream>>>(S);

    // 4) y = P . V via Vt, causal K truncation
    gemm_bt<2><<<dim3(8, 16, 4), blk, 0, stream>>>((__bf16*)S, Vt, out,
        2048, 4096, 2048, 1024, 2048L * 4096, 1024L * 2048, 2048L * 1024);
}